// Round 15
// baseline (1967.180 us; speedup 1.0000x reference)
//
#include <hip/hip_runtime.h>
#include <math.h>

#define NWG 256
#define TPB 1024

static constexpr int Bc=128, Ic=256, Hc=512, NCc=16, Tc=24, Mc=14;
static constexpr int Y_SZ  = Bc*NCc*Tc;     // 49152
static constexpr int P_OFF = Y_SZ;          // 49152
static constexpr int N_OFF = Y_SZ + Bc;     // 49280

// ws layout (floats) -- total 331776 floats = 1.27 MiB (< 1.375 proven)
static constexpr int HSZ    = Hc*Bc;                  // 65536
static constexpr int HB_OFF = 0;                      // hbuf[2][512][128]
static constexpr int SC_OFF = 2*HSZ;                  // stc[2][512][128]
static constexpr int HP_OFF = 4*HSZ;                  // hpp[2][16][128]
static constexpr int DP_OFF = HP_OFF + 2*2048;        // decp[2][16][16][128]

typedef float f4v __attribute__((ext_vector_type(4)));

// Barrier state: 16-group arrival tree + single root watermark. 64B lines.
__device__ __align__(64) unsigned g_bcnt[16][16];
__device__ __align__(64) unsigned g_brc[16];
__device__ __align__(64) unsigned g_brg[16];

__device__ __forceinline__ float sigm(float v){ return 1.0f/(1.0f+expf(-v)); }

// PRODUCER: system-scope write-through stores (sc0 sc1) -> coherent at IF.
__device__ __forceinline__ void gstore(float* p, float v){
  __hip_atomic_store(p, v, __ATOMIC_RELAXED, __HIP_MEMORY_SCOPE_SYSTEM);
}

// Two-level arrival tree, ROOT-DIRECT release: all leaders poll the root
// watermark (no group-gen broadcast hop). Monotonic episodes: a leader can
// only arrive for episode e+1 after passing episode e's poll, so per-line
// counts stay in lockstep; (prev&15)==15 detects the 16th arrival.
__device__ __forceinline__ void gsync(int w){
  __syncthreads();
  if (threadIdx.x == 0) {
    asm volatile("" ::: "memory");
    const int g = w >> 4;
    unsigned prev = __hip_atomic_fetch_add(&g_bcnt[g][0], 1u, __ATOMIC_RELAXED, __HIP_MEMORY_SCOPE_SYSTEM);
    unsigned ep   = prev >> 4;
    if ((prev & 15u) == 15u) {
      unsigned rprev = __hip_atomic_fetch_add(&g_brc[0], 1u, __ATOMIC_RELAXED, __HIP_MEMORY_SCOPE_SYSTEM);
      if ((rprev & 15u) == 15u)
        __hip_atomic_store(&g_brg[0], (rprev >> 4) + 1u, __ATOMIC_RELEASE, __HIP_MEMORY_SCOPE_SYSTEM);
    }
    while ((int)(__hip_atomic_load(&g_brg[0], __ATOMIC_RELAXED, __HIP_MEMORY_SCOPE_SYSTEM) - (ep + 1u)) < 0)
      ;   // busy poll: detection latency = one uncached load RTT
    asm volatile("" ::: "memory");
  }
  __syncthreads();
}

__global__ __launch_bounds__(TPB, 1) void act_lstm_kernel(
    const float* __restrict__ x,   const float* __restrict__ Wih,
    const float* __restrict__ Whh, const float* __restrict__ bih,
    const float* __restrict__ bhh, const float* __restrict__ hw,
    const float* __restrict__ hbp, const float* __restrict__ dw,
    const float* __restrict__ db,  float* __restrict__ out,
    float* __restrict__ ws)
{
  const int w    = blockIdx.x;
  const int tid  = threadIdx.x;
  const int lane = tid & 63;
  const int wid  = __builtin_amdgcn_readfirstlane(tid >> 6); // 0..15 = k/i-chunk
  const int xcg  = w & 7, xidx = w >> 3;
  const int js   = (xcg << 1) | (xidx & 1);   // j-slice [0,16)
  const int bg   = xidx >> 1;                 // batch group [0,16)
  const int kg   = wid;              // wave's k-chunk (h: 32 k, x: 16 i)
  const int rl0  = lane, rl1 = lane + 64;
  const int grow0 = ((rl0>>5)<<9) + js*32 + (rl0&31);
  const int grow1 = ((rl1>>5)<<9) + js*32 + (rl1&31);
  const bool iscell = (tid < 256);
  const int jloc = tid >> 3, bl = tid & 7;
  const int jglob = js*32 + jloc;
  const int bglob = bg*8 + bl;

  float* hbuf = ws + HB_OFF;
  float* stc  = ws + SC_OFF;
  float* hpp  = ws + HP_OFF;
  float* decp = ws + DP_OFF;

  __shared__ float h_lds[4096];       // [j 512][b 8]
  __shared__ float x_lds[2048];       // [i 256][b 8]
  __shared__ float part[128*129];     // [row][kg*8+b], stride 129
  __shared__ float sums[1024];        // [row*8+b]
  __shared__ float dp[4096];          // [nc 16][jloc 32][b 8]
  __shared__ float hp[256];
  __shared__ float pmh[128];
  __shared__ float hq[2048];          // staged hpp (phase B)
  __shared__ float pnl[128];
  __shared__ float dy[128];           // staged decp for nc=js (pend-Y)
  __shared__ unsigned ldsu[2];

  const f4v* Wh0 = (const f4v*)(Whh + grow0*Hc) + kg*8;  // 8 f4 (32 k)
  const f4v* Wh1 = (const f4v*)(Whh + grow1*Hc) + kg*8;
  const f4v* Wx0 = (const f4v*)(Wih + grow0*Ic) + kg*4;  // 4 f4 (16 i)
  const f4v* Wx1 = (const f4v*)(Wih + grow1*Ic) + kg*4;

  float bsum[4] = {0,0,0,0};
  float hwj = 0.f;
  if (iscell) {
    #pragma unroll
    for (int g=0; g<4; ++g) bsum[g] = bih[g*512 + jglob] + bhh[g*512 + jglob];
    hwj = hw[jglob];
  }
  const float hb0 = hbp[0];

  // persistent state
  float c = 0.f, st_run = 0.f, ct_run = 0.f, prev_pm = 0.f;          // cell
  float cumw=0.f, prevw=0.f, ntfw=0.f, rtvw=0.f, psumw=0.f;          // tracker (wid<2)
  bool  ntsetw = false;
  int   gt = 0, lastpar = 0, pend_t = -1, pend_par = 0;
  float xg[4] = {0,0,0,0};
  f4v   spec = {0,0,0,0};             // speculative next-tick h (continue path)
  bool  have_spec = false;

  for (int t = 0; t < Tc; ++t) {
    for (int mm = 0;; ++mm) {
      const bool do_h = !(mm == 0 && t == 0);
      float xv0 = 0.f, xv1 = 0.f;
      if (mm == 0) {
        const int i0 = tid >> 3, b0 = tid & 7;
        const int xb = (bg*8 + b0) * (Ic*Tc);
        xv0 = x[xb + i0*Tc + t];
        xv1 = x[xb + (i0+128)*Tc + t];
      }
      // ---- h slice into LDS: speculative reg (mm>0) or volatile f4 load ----
      if (do_h) {
        if (mm > 0 && have_spec) {
          *(f4v*)&h_lds[tid*4] = spec;     // prefetched during last phase B
        } else {
          const float* src = (mm == 0) ? (stc + lastpar*HSZ) : (hbuf + ((gt-1)&1)*HSZ);
          const int j = tid >> 1, q = tid & 1;
          f4v hv = *(const volatile f4v*)(src + j*128 + bg*8 + q*4);
          *(f4v*)&h_lds[tid*4] = hv;
        }
      }
      __syncthreads();

      if (mm == 0) {
        x_lds[tid]        = xv0;       // layout [i*8+b] == tid
        x_lds[tid + 1024] = xv1;
        __syncthreads();
        // ---- x-GEMV: rows {rl0,rl1} x i-chunk 16 x 8 b ----
        float a0[8] = {0,0,0,0,0,0,0,0}, a1[8] = {0,0,0,0,0,0,0,0};
        #pragma unroll
        for (int c4 = 0; c4 < 4; ++c4) {
          f4v w0 = Wx0[c4], w1 = Wx1[c4];
          #pragma unroll
          for (int d = 0; d < 4; ++d) {
            const float wa = w0[d], wb = w1[d];
            const float* hbp_ = &x_lds[(kg*16 + c4*4 + d)*8];
            f4v hA = *(const f4v*)hbp_, hB = *(const f4v*)(hbp_+4);
            a0[0]=fmaf(wa,hA.x,a0[0]); a0[1]=fmaf(wa,hA.y,a0[1]);
            a0[2]=fmaf(wa,hA.z,a0[2]); a0[3]=fmaf(wa,hA.w,a0[3]);
            a0[4]=fmaf(wa,hB.x,a0[4]); a0[5]=fmaf(wa,hB.y,a0[5]);
            a0[6]=fmaf(wa,hB.z,a0[6]); a0[7]=fmaf(wa,hB.w,a0[7]);
            a1[0]=fmaf(wb,hA.x,a1[0]); a1[1]=fmaf(wb,hA.y,a1[1]);
            a1[2]=fmaf(wb,hA.z,a1[2]); a1[3]=fmaf(wb,hA.w,a1[3]);
            a1[4]=fmaf(wb,hB.x,a1[4]); a1[5]=fmaf(wb,hB.y,a1[5]);
            a1[6]=fmaf(wb,hB.z,a1[6]); a1[7]=fmaf(wb,hB.w,a1[7]);
          }
        }
        #pragma unroll
        for (int b = 0; b < 8; ++b) {
          part[rl0*129 + kg*8 + b] = a0[b];
          part[rl1*129 + kg*8 + b] = a1[b];
        }
        __syncthreads();
        {
          const int row = tid >> 3, b = tid & 7;
          float s = 0.f;
          #pragma unroll
          for (int q2 = 0; q2 < 16; ++q2) s += part[row*129 + q2*8 + b];
          sums[tid] = s;
        }
        __syncthreads();
        if (iscell) {
          #pragma unroll
          for (int g = 0; g < 4; ++g) xg[g] = bsum[g] + sums[(g*32 + jloc)*8 + bl];
        }
        __syncthreads();
      }

      // ---- h-GEMV: rows {rl0,rl1} x k-chunk 32 x 8 b ----
      {
        float a0[8] = {0,0,0,0,0,0,0,0}, a1[8] = {0,0,0,0,0,0,0,0};
        if (do_h) {
          #pragma unroll
          for (int c4 = 0; c4 < 8; ++c4) {
            f4v w0 = Wh0[c4], w1 = Wh1[c4], w2, w3;
            #pragma unroll
            for (int d = 0; d < 4; ++d) {
              const float wa = w0[d], wb = w1[d];
              const float* hbp_ = &h_lds[(kg*32 + c4*4 + d)*8];
              f4v hA = *(const f4v*)hbp_, hB = *(const f4v*)(hbp_+4);
              a0[0]=fmaf(wa,hA.x,a0[0]); a0[1]=fmaf(wa,hA.y,a0[1]);
              a0[2]=fmaf(wa,hA.z,a0[2]); a0[3]=fmaf(wa,hA.w,a0[3]);
              a0[4]=fmaf(wa,hB.x,a0[4]); a0[5]=fmaf(wa,hB.y,a0[5]);
              a0[6]=fmaf(wa,hB.z,a0[6]); a0[7]=fmaf(wa,hB.w,a0[7]);
              a1[0]=fmaf(wb,hA.x,a1[0]); a1[1]=fmaf(wb,hA.y,a1[1]);
              a1[2]=fmaf(wb,hA.z,a1[2]); a1[3]=fmaf(wb,hA.w,a1[3]);
              a1[4]=fmaf(wb,hB.x,a1[4]); a1[5]=fmaf(wb,hB.y,a1[5]);
              a1[6]=fmaf(wb,hB.z,a1[6]); a1[7]=fmaf(wb,hB.w,a1[7]);
            }
            (void)w2; (void)w3;
          }
        }
        #pragma unroll
        for (int b = 0; b < 8; ++b) {
          part[rl0*129 + kg*8 + b] = a0[b];
          part[rl1*129 + kg*8 + b] = a1[b];
        }
      }
      __syncthreads();
      {
        const int row = tid >> 3, b = tid & 7;
        float s = 0.f;
        #pragma unroll
        for (int q2 = 0; q2 < 16; ++q2) s += part[row*129 + q2*8 + b];
        sums[tid] = s;
      }
      __syncthreads();

      // ---- LSTM cell (i,f,g,o) ----
      float hn = 0.f, cn = 0.f;
      if (iscell) {
        float g0 = xg[0] + sums[(0*32 + jloc)*8 + bl];
        float g1 = xg[1] + sums[(1*32 + jloc)*8 + bl];
        float g2 = xg[2] + sums[(2*32 + jloc)*8 + bl];
        float g3 = xg[3] + sums[(3*32 + jloc)*8 + bl];
        float ig = sigm(g0), fg = sigm(g1), gg = tanhf(g2), og = sigm(g3);
        cn = fg*c + ig*gg;
        hn = og*tanhf(cn);
        const int par = gt & 1;
        gstore(hbuf + par*HSZ + jglob*128 + bglob, hn);
        gstore(stc  + par*HSZ + jglob*128 + bglob, st_run + (1.f - prev_pm)*hn);
        hp[tid] = hn * hwj;
      }
      __syncthreads();
      if (tid < 8) {
        float s = 0.f;
        #pragma unroll
        for (int jl = 0; jl < 32; ++jl) s += hp[jl*8 + tid];
        gstore(hpp + (gt&1)*2048 + js*128 + bg*8 + tid, s);
      }

      gsync(w);

      // ---- phase B ----
      const int par = gt & 1;
      // hq staging FIRST (decision-critical); spec prefetch LAST so its RTT
      // queues behind hq, not ahead of it, on tid<512.
      if (tid < 512) {
        f4v v = *(const volatile f4v*)(hpp + par*2048 + tid*4);
        *(f4v*)&hq[tid*4] = v;
      } else if (pend_t >= 0 && tid < 544) {
        const int js2 = (tid - 512) >> 1, hf = tid & 1;
        f4v v = *(const volatile f4v*)(decp + pend_par*32768 + js2*2048 + js*128 + bg*8 + hf*4);
        *(f4v*)&dy[js2*8 + hf*4] = v;
      }
      {
        const int j = tid >> 1, q = tid & 1;
        spec = *(const volatile f4v*)(hbuf + par*HSZ + j*128 + bg*8 + q*4);
        have_spec = true;
      }
      __syncthreads();
      if (tid < 128) {
        float s = 0.f;
        #pragma unroll
        for (int js2 = 0; js2 < 16; ++js2) s += hq[js2*128 + tid];
        pnl[tid] = s;
      } else if (pend_t >= 0 && tid >= 256 && tid < 264) {
        const int b2 = tid - 256;
        float y = 0.f;
        #pragma unroll
        for (int js2 = 0; js2 < 16; ++js2) y += dy[js2*8 + b2];
        out[((bg*8 + b2)*NCc + js)*Tc + pend_t] = y + db[js];
      }
      __syncthreads();
      pend_t = -1;
      if (wid < 2) {
        const int b2 = wid*64 + lane;
        float pn = sigm(pnl[b2] + hb0);
        cumw += pn;
        int ok = __all(cumw >= 0.99f) ? 1 : 0;
        if (lane == 0) ldsu[wid] = (unsigned)ok;
        pmh[b2] = fminf(1.f, cumw);
      }
      __syncthreads();
      const int finv = (((ldsu[0] & ldsu[1]) != 0u) || (mm == Mc-1)) ? 1 : 0;

      if (wid < 2) {
        float pmf = finv ? 1.f : fminf(1.f, cumw);
        if (!ntsetw && pmf >= 1.f) {
          ntfw = (float)mm;
          rtvw = (mm == 0) ? 0.f : (1.f - prevw);
          ntsetw = true;
        }
        prevw = pmf;
      }
      if (iscell) {
        float pm = finv ? 1.f : pmh[bglob];
        float ph = pm - prev_pm;
        st_run += ph*hn;
        ct_run += ph*cn;
        prev_pm = pm;
        c = finv ? ct_run : cn;
      }
      if (finv) {
        if (iscell) {
          #pragma unroll
          for (int nc = 0; nc < 16; ++nc)
            dp[nc*256 + tid] = dw[nc*512 + jglob] * st_run;
        }
        __syncthreads();
        if (tid < 128) {
          const int nc = tid >> 3, b2 = tid & 7;
          float s = 0.f;
          #pragma unroll
          for (int jl = 0; jl < 32; ++jl) s += dp[nc*256 + jl*8 + b2];
          gstore(decp + par*32768 + js*2048 + nc*128 + bg*8 + b2, s);
        }
        if (bg == 0 && js == 0 && wid < 2)
          out[N_OFF + (wid*64 + lane)*Tc + t] = ntfw;
        if (wid < 2) {
          psumw += ntfw + rtvw;
          ntsetw = false; prevw = 0.f; cumw = 0.f; ntfw = 0.f; rtvw = 0.f;
        }
        if (iscell) { st_run = 0.f; ct_run = 0.f; prev_pm = 0.f; }
        pend_t = t; pend_par = par; lastpar = par;
      }
      ++gt;
      if (finv) break;
    }
  }

  // ---- epilogue: Y for t=23 (distributed, nc=js), P ----
  gsync(w);
  if (pend_t >= 0) {
    if (tid < 32) {
      const int js2 = tid >> 1, hf = tid & 1;
      f4v v = *(const volatile f4v*)(decp + pend_par*32768 + js2*2048 + js*128 + bg*8 + hf*4);
      *(f4v*)&dy[js2*8 + hf*4] = v;
    }
    __syncthreads();
    if (tid < 8) {
      float y = 0.f;
      #pragma unroll
      for (int js2 = 0; js2 < 16; ++js2) y += dy[js2*8 + tid];
      out[((bg*8 + tid)*NCc + js)*Tc + pend_t] = y + db[js];
    }
  }
  if (bg == 0 && js == 1 && wid < 2) out[P_OFF + wid*64 + lane] = psumw;
}

extern "C" void kernel_launch(void* const* d_in, const int* in_sizes, int n_in,
                              void* d_out, int out_size, void* d_ws, size_t ws_size,
                              hipStream_t stream) {
  const float* x   = (const float*)d_in[0];
  const float* Wih = (const float*)d_in[1];
  const float* Whh = (const float*)d_in[2];
  const float* bih = (const float*)d_in[3];
  const float* bhh = (const float*)d_in[4];
  const float* hw  = (const float*)d_in[5];
  const float* hb  = (const float*)d_in[6];
  const float* dwp = (const float*)d_in[7];
  const float* dbp = (const float*)d_in[8];
  float* out = (float*)d_out;
  float* ws  = (float*)d_ws;

  void* kargs[] = {(void*)&x, (void*)&Wih, (void*)&Whh, (void*)&bih, (void*)&bhh,
                   (void*)&hw, (void*)&hb, (void*)&dwp, (void*)&dbp, (void*)&out, (void*)&ws};
  hipLaunchCooperativeKernel((void*)act_lstm_kernel, dim3(NWG), dim3(TPB),
                             kargs, 0, stream);
}